// Round 6
// baseline (282.624 us; speedup 1.0000x reference)
//
#include <hip/hip_runtime.h>

#define SEQ 2048
#define HID 2048
#define NH  32
#define NKV 8
#define HD  64

typedef _Float16 f16;
typedef __attribute__((ext_vector_type(4))) _Float16 f16x4;
typedef __attribute__((ext_vector_type(8))) _Float16 f16x8;
typedef __attribute__((ext_vector_type(2))) __fp16   h16x2;
typedef __attribute__((ext_vector_type(4))) float    f32x4;

__device__ __forceinline__ f32x4 mfma_16x16x32(f16x8 a, f16x8 b, f32x4 c) {
    return __builtin_amdgcn_mfma_f32_16x16x32_f16(a, b, c, 0, 0, 0);
}

// async global->LDS, 16B per lane. Global address is PER-LANE (gather);
// LDS dest is wave-uniform base + lane*16 (contiguous).
__device__ __forceinline__ void async16(const void* g, void* l) {
    __builtin_amdgcn_global_load_lds(
        (const __attribute__((address_space(1))) void*)g,
        (__attribute__((address_space(3))) void*)l,
        16, 0, 0);
}

// Bijective XCD remap, column-chunked (m204 variant).
__device__ __forceinline__ void xcd_colmap(int& bx, int& by) {
    int gx = gridDim.x, gy = gridDim.y;
    int nwg = gx * gy;
    int orig = by * gx + bx;
    int q = nwg >> 3, r = nwg & 7;
    int xcd = orig & 7, loc = orig >> 3;
    int wg = (xcd < r ? xcd * (q + 1) : r * (q + 1) + (xcd - r) * q) + loc;
    bx = wg / gy;
    by = wg - bx * gy;
}

// ---------------- prep: vectorized transposes + cvt (G13) ----------------------
__global__ void prep_all(const float* __restrict__ x,
                         const float* __restrict__ wq, const float* __restrict__ wk,
                         const float* __restrict__ wv, const float* __restrict__ wo,
                         f16* __restrict__ xb,
                         f16* __restrict__ Wcat, f16* __restrict__ woT) {
    __shared__ float ft[64 * 65];
    int z = blockIdx.z;
    int tid = threadIdx.x;            // 256 threads
    if (z == 4) {                     // cvt: 2048*2048 flat, grid (32,32)
        int base = (blockIdx.y * 32 + blockIdx.x) * 4096 + tid * 8;
#pragma unroll
        for (int i = 0; i < 2; i++) {
            int off = base + i * 2048;
            float4 a = *(const float4*)(x + off);
            float4 b = *(const float4*)(x + off + 4);
            f16x8 o = { (f16)a.x, (f16)a.y, (f16)a.z, (f16)a.w,
                        (f16)b.x, (f16)b.y, (f16)b.z, (f16)b.w };
            *(f16x8*)(xb + off) = o;
        }
        return;
    }
    const float* src; f16* dst; int C;
    if      (z == 0) { src = wq; dst = Wcat;                         C = 2048; }
    else if (z == 1) { src = wk; dst = Wcat + (size_t)2048 * 2048;   C = 512;  }
    else if (z == 2) { src = wv; dst = Wcat + (size_t)2560 * 2048;   C = 512;  }
    else             { src = wo; dst = woT;                          C = 2048; }
    int c0 = blockIdx.x * 64, r0 = blockIdx.y * 64;
    if (c0 >= C) return;
    int c4 = tid & 15;
#pragma unroll
    for (int i = 0; i < 4; i++) {
        int r = (tid >> 4) * 4 + i;
        float4 v = *(const float4*)(src + (size_t)(r0 + r) * C + c0 + c4 * 4);
        *(float4*)(&ft[r * 65 + c4 * 4]) = v;
    }
    __syncthreads();
    int q = tid & 7;
#pragma unroll
    for (int it = 0; it < 2; it++) {
        int jj = (tid >> 3) + it * 32;
        f16x8 v;
#pragma unroll
        for (int e = 0; e < 8; e++)
            v[e] = (f16)ft[(q * 8 + e) * 65 + jj];
        *(f16x8*)(dst + (size_t)(c0 + jj) * 2048 + r0 + q * 8) = v;
    }
}

// ---------------- GEMM: C[M,N] = A[M,K] @ BT[N,K]^T (round-1 known-good) -------
// BM x 128 tile, BK=64, 4 waves 2x2, dbuf staging with XOR-swizzled k-chunks.
// Plain __syncthreads loop (pins/setprio regressed — m141/m190). BM=64 both.
template <int MODE, int BM>
__global__ __launch_bounds__(256)
void gemm_bt(const f16* __restrict__ A, const f16* __restrict__ BT,
             float* __restrict__ Cf, f16* __restrict__ Q, f16* __restrict__ Kk,
             f16* __restrict__ VT, const int* __restrict__ pos,
             const float* __restrict__ mask, int N, int K) {
    constexpr int MI = BM / 32;      // acc rows / af frags per wave
    constexpr int AR = BM / 4;       // A rows staged per wave
    __shared__ f16 As[2][BM * 64];   // [row][k-chunk swizzled]
    __shared__ f16 Bs[2][128 * 64];
    int t = threadIdx.x;
    int w = t >> 6, lane = t & 63, quad = lane >> 4, l15 = lane & 15;
    int wm = w >> 1, wn = w & 1;
    int bx = blockIdx.x, by = blockIdx.y;
    xcd_colmap(bx, by);
    int m0 = by * BM, n0 = bx * 128;
    int sw = l15 & 7;

    int r8 = lane >> 3;            // row within 8-row staging group
    int cc = (lane & 7) ^ r8;      // XOR-swizzled global k-chunk
    const f16* Ag = A  + (size_t)(m0 + w * AR + r8) * K + cc * 8;
    const f16* Bg = BT + (size_t)(n0 + w * 32 + r8) * K + cc * 8;

    f32x4 acc[MI][4] = {};

    // stage tile 0
#pragma unroll
    for (int a = 0; a < AR / 8; a++)
        async16(Ag + (size_t)(8 * a) * K, &As[0][(w * AR + 8 * a) * 64]);
#pragma unroll
    for (int g = 0; g < 4; g++)
        async16(Bg + (size_t)(8 * g) * K, &Bs[0][(w * 32 + 8 * g) * 64]);
    __syncthreads();

    int b = 0;
    for (int kt = 64; kt <= K; kt += 64) {
        if (kt < K) {
#pragma unroll
            for (int a = 0; a < AR / 8; a++)
                async16(Ag + (size_t)(8 * a) * K + kt, &As[b ^ 1][(w * AR + 8 * a) * 64]);
#pragma unroll
            for (int g = 0; g < 4; g++)
                async16(Bg + (size_t)(8 * g) * K + kt, &Bs[b ^ 1][(w * 32 + 8 * g) * 64]);
        }
        f16x8 af[MI][2], bf[4][2];
#pragma unroll
        for (int mi = 0; mi < MI; mi++) {
            int row = wm * (BM / 2) + mi * 16 + l15;
#pragma unroll
            for (int kh = 0; kh < 2; kh++)
                af[mi][kh] = *(const f16x8*)(&As[b][row * 64 + ((kh * 4 + quad) ^ sw) * 8]);
        }
#pragma unroll
        for (int ni = 0; ni < 4; ni++) {
            int row = wn * 64 + ni * 16 + l15;
#pragma unroll
            for (int kh = 0; kh < 2; kh++)
                bf[ni][kh] = *(const f16x8*)(&Bs[b][row * 64 + ((kh * 4 + quad) ^ sw) * 8]);
        }
#pragma unroll
        for (int mi = 0; mi < MI; mi++)
#pragma unroll
            for (int ni = 0; ni < 4; ni++) {
                acc[mi][ni] = mfma_16x16x32(af[mi][0], bf[ni][0], acc[mi][ni]);
                acc[mi][ni] = mfma_16x16x32(af[mi][1], bf[ni][1], acc[mi][ni]);
            }
        __syncthreads();
        b ^= 1;
    }

    int rb  = m0 + wm * (BM / 2) + quad * 4;
    int cbh = n0 + wn * 64;          // 64-aligned: one head per wave column
    if (MODE == 0) {
        if (cbh < (NH + NKV) * HD) {
            bool isQ = cbh < NH * HD;
            f16* dst = isQ ? (Q  + (size_t)(cbh >> 6) * SEQ * HD)
                           : (Kk + (size_t)((cbh - NH * HD) >> 6) * SEQ * HD);
            float scale = isQ ? 0.18033688011112042f : 1.0f;  // (1/8)*log2(e)
            float fr[2];
#pragma unroll
            for (int ni = 0; ni < 2; ni++)
                fr[ni] = __builtin_amdgcn_exp2f(
                    (float)(ni * 16 + l15) * -0.41524101186092029f); // -log2(1e4)/32
#pragma unroll
            for (int mi = 0; mi < MI; mi++)
#pragma unroll
                for (int r = 0; r < 4; r++) {
                    int row = rb + mi * 16 + r;
                    float pv = (float)pos[row];
#pragma unroll
                    for (int ni = 0; ni < 2; ni++) {
                        float sn, cs;
                        __sincosf(pv * fr[ni], &sn, &cs);
                        float x1 = acc[mi][ni][r], x2 = acc[mi][ni + 2][r];
                        int d = ni * 16 + l15;
                        dst[(size_t)row * HD + d]      = (f16)(scale * (x1 * cs - x2 * sn));
                        dst[(size_t)row * HD + d + 32] = (f16)(scale * (x2 * cs + x1 * sn));
                    }
                }
        } else {
            // ---- V^T with mask folded in: VT[c2][s] = v * exp2(mask[s]*log2e).
            const float LOG2E = 1.4426950408889634f;
#pragma unroll
            for (int mi = 0; mi < MI; mi++) {
                float4 mv = *(const float4*)(mask + rb + mi * 16);
                float em[4];
#pragma unroll
                for (int r = 0; r < 4; r++)
                    em[r] = __builtin_amdgcn_exp2f((&mv.x)[r] * LOG2E);
#pragma unroll
                for (int ni = 0; ni < 4; ni++) {
                    int c2 = cbh - (NH + NKV) * HD + ni * 16 + l15;
                    f16x4 v4;
                    ((h16x2*)&v4)[0] = __builtin_amdgcn_cvt_pkrtz(
                        acc[mi][ni][0] * em[0], acc[mi][ni][1] * em[1]);
                    ((h16x2*)&v4)[1] = __builtin_amdgcn_cvt_pkrtz(
                        acc[mi][ni][2] * em[2], acc[mi][ni][3] * em[3]);
                    *(f16x4*)(VT + (size_t)c2 * SEQ + rb + mi * 16) = v4;
                }
            }
        }
    } else {
#pragma unroll
        for (int mi = 0; mi < MI; mi++)
#pragma unroll
            for (int ni = 0; ni < 4; ni++)
#pragma unroll
                for (int r = 0; r < 4; r++)
                    Cf[(size_t)(rb + mi * 16 + r) * N + cbh + ni * 16 + l15] =
                        acc[mi][ni][r];
    }
}

// ---------------- fused flash attention: 8 waves, DIRECT L1/L2 K/V loads -------
// grid (SEQ/256, NH) = 256 blocks x 512 threads. K+V per kv-head = 512 KB
// (L2-resident; per-tile working set 16 KB fits L1, so 7 of 8 waves hit L1)
// => NO LDS staging, NO main-loop barriers (m169 precedent: dropping staging
// of L2-fit data was +26%). Each wave loads its MFMA fragments directly with
// perfectly-coalesced global_load_dwordx4 (16 rows x 64B per instr). The
// K-row permutation g() is folded into per-lane addresses (bit-identical
// operands vs the staged version). Only Em stays in LDS (one barrier).
// Waves drift freely — the LDS serialization that capped the staged version
// at ~53% of its pipe floor is gone. VGPR-capped to 2 waves/SIMD.
__global__ __launch_bounds__(512, 2)
void attn_fused(const f16* __restrict__ Qb, const f16* __restrict__ Kb,
                const f16* __restrict__ VTb, const float* __restrict__ mask,
                f16* __restrict__ ctx) {
    __shared__ f16 Em[SEQ];

    int t = threadIdx.x, w = t >> 6, lane = t & 63, quad = lane >> 4, l15 = lane & 15;
    int h = blockIdx.y, kvh = h >> 2;
    int qbase = blockIdx.x * 256 + w * 32;
    const f16* Qh = Qb  + (size_t)h   * SEQ * HD;
    const f16* Kh = Kb  + (size_t)kvh * SEQ * HD;
    const f16* Vh = VTb + (size_t)kvh * HD * SEQ;
    const float LOG2E = 1.4426950408889634f;

    // ---- Em = exp2(mask*log2e) for full SEQ (one f16x4 per thread) ----
    {
        int idx = t * 4;
        float4 mv = *(const float4*)(mask + idx);
        f16x4 e;
        ((h16x2*)&e)[0] = __builtin_amdgcn_cvt_pkrtz(
            __builtin_amdgcn_exp2f(mv.x * LOG2E), __builtin_amdgcn_exp2f(mv.y * LOG2E));
        ((h16x2*)&e)[1] = __builtin_amdgcn_cvt_pkrtz(
            __builtin_amdgcn_exp2f(mv.z * LOG2E), __builtin_amdgcn_exp2f(mv.w * LOG2E));
        *(f16x4*)(&Em[idx]) = e;
    }

    // ---- Q fragments (persistent): B-operand of S^T, n = q ----
    f16x8 bq[2][2];
#pragma unroll
    for (int qg = 0; qg < 2; qg++)
#pragma unroll
        for (int ks = 0; ks < 2; ks++)
            bq[qg][ks] = *(const f16x8*)(Qh + (size_t)(qbase + qg * 16 + l15) * HD
                                            + ks * 32 + quad * 8);

    f32x4 o[4][2] = {};          // O^T: [d-tile][q-group]
    f32x4 ol[2]   = {};          // l accumulator (all rows identical)

    // per-lane permuted K-row base: rr = ni*16+l15 maps to global key
    // gk = 32*(ni>>1) + 4*(ni&1) + 8*(l15>>2) + (l15&3)  (ni part via nio[])
    int gkb = 8 * (l15 >> 2) + (l15 & 3);
    const f16* Kl = Kh + (size_t)gkb * HD + quad * 8;
    const f16* Vl = Vh + (size_t)l15 * SEQ + quad * 8;

    __syncthreads();             // Em visible to all waves; only barrier.

#pragma unroll 1
    for (int ktl = 0; ktl < SEQ / 64; ktl++) {
        int key0 = ktl * 64;
        // ---- V fragments first (consumed last: ~full-tile latency cover) ----
        f16x8 vf[4][2];
#pragma unroll
        for (int dt = 0; dt < 4; dt++)
#pragma unroll
            for (int kh = 0; kh < 2; kh++)
                vf[dt][kh] = *(const f16x8*)(Vl + (size_t)(dt * 16) * SEQ
                                                + key0 + kh * 32);
        // ---- K fragments (permuted row order) ----
        f16x8 kf[4][2];
#pragma unroll
        for (int ni = 0; ni < 4; ni++) {
            const int nio = (ni >> 1) * 32 + (ni & 1) * 4;
#pragma unroll
            for (int kh = 0; kh < 2; kh++)
                kf[ni][kh] = *(const f16x8*)(Kl + (size_t)(key0 + nio) * HD
                                                + kh * 32);
        }
        // ---- S^T = K @ Q^T ----
        f32x4 st[4][2] = {};
        __builtin_amdgcn_s_setprio(1);
#pragma unroll
        for (int ni = 0; ni < 4; ni++)
#pragma unroll
            for (int qg = 0; qg < 2; qg++) {
                st[ni][qg] = mfma_16x16x32(kf[ni][0], bq[qg][0], st[ni][qg]);
                st[ni][qg] = mfma_16x16x32(kf[ni][1], bq[qg][1], st[ni][qg]);
            }
        __builtin_amdgcn_s_setprio(0);
        // ---- p = exp2(s) (mask lives in V); pack via cvt_pkrtz ----
        f16x8 pb[2][2];   // [qg][ks]
#pragma unroll
        for (int ni = 0; ni < 4; ni++)
#pragma unroll
            for (int qg = 0; qg < 2; qg++) {
                h16x2 lo = __builtin_amdgcn_cvt_pkrtz(
                    __builtin_amdgcn_exp2f(st[ni][qg][0]),
                    __builtin_amdgcn_exp2f(st[ni][qg][1]));
                h16x2 hi = __builtin_amdgcn_cvt_pkrtz(
                    __builtin_amdgcn_exp2f(st[ni][qg][2]),
                    __builtin_amdgcn_exp2f(st[ni][qg][3]));
                ((h16x2*)&pb[qg][ni >> 1])[(ni & 1) * 2]     = lo;
                ((h16x2*)&pb[qg][ni >> 1])[(ni & 1) * 2 + 1] = hi;
            }
        // ---- l += em-row @ P ----
        f16x8 em0 = *(const f16x8*)(&Em[key0 + quad * 8]);
        f16x8 em1 = *(const f16x8*)(&Em[key0 + 32 + quad * 8]);
        __builtin_amdgcn_s_setprio(1);
#pragma unroll
        for (int qg = 0; qg < 2; qg++) {
            ol[qg] = mfma_16x16x32(em0, pb[qg][0], ol[qg]);
            ol[qg] = mfma_16x16x32(em1, pb[qg][1], ol[qg]);
        }
        // ---- O^T += V^T @ P ----
#pragma unroll
        for (int dt = 0; dt < 4; dt++)
#pragma unroll
            for (int qg = 0; qg < 2; qg++) {
                o[dt][qg] = mfma_16x16x32(vf[dt][0], pb[qg][0], o[dt][qg]);
                o[dt][qg] = mfma_16x16x32(vf[dt][1], pb[qg][1], o[dt][qg]);
            }
        __builtin_amdgcn_s_setprio(0);
    }

    // ---- normalize in-register, write ctx[row][h*64+d] directly ----
    float inv[2] = { 1.0f / ol[0][0], 1.0f / ol[1][0] };
#pragma unroll
    for (int dt = 0; dt < 4; dt++)
#pragma unroll
        for (int qg = 0; qg < 2; qg++) {
            f16x4 v4;
            ((h16x2*)&v4)[0] = __builtin_amdgcn_cvt_pkrtz(
                o[dt][qg][0] * inv[qg], o[dt][qg][1] * inv[qg]);
            ((h16x2*)&v4)[1] = __builtin_amdgcn_cvt_pkrtz(
                o[dt][qg][2] * inv[qg], o[dt][qg][3] * inv[qg]);
            *(f16x4*)(ctx + (size_t)(qbase + qg * 16 + l15) * (NH * HD)
                          + h * HD + dt * 16 + quad * 4) = v4;
        }
}

// ---------------- launch ----------------
extern "C" void kernel_launch(void* const* d_in, const int* in_sizes, int n_in,
                              void* d_out, int out_size, void* d_ws, size_t ws_size,
                              hipStream_t stream) {
    const float* x    = (const float*)d_in[0];
    const float* mask = (const float*)d_in[1];
    const int*   pos  = (const int*)  d_in[2];
    const float* wq   = (const float*)d_in[3];
    const float* wk   = (const float*)d_in[4];
    const float* wv   = (const float*)d_in[5];
    const float* wo   = (const float*)d_in[6];
    float* out = (float*)d_out;

    char* ws = (char*)d_ws;
    // phase 1-2: xb [0,8M), Wcat [8,20M), woT [20,28M), Qb [28,36M),
    //            Kb [36,38M), VTb [38,40M)
    // phase 3:   ctx [0,8M) (xb dead after gemm0)
    // phase 4:   gemm1 reads ctx + woT
    f16*   xb    = (f16*)(ws);
    f16*   Wcat  = (f16*)(ws + ((size_t)8  << 20));
    f16*   woT   = (f16*)(ws + ((size_t)20 << 20));
    f16*   Qb    = (f16*)(ws + ((size_t)28 << 20));
    f16*   Kb    = (f16*)(ws + ((size_t)36 << 20));
    f16*   VTb   = (f16*)(ws + ((size_t)38 << 20));
    f16*   ctx   = (f16*)(ws);

    prep_all<<<dim3(32, 32, 5), 256, 0, stream>>>(
        x, wq, wk, wv, wo, xb, Wcat, woT);

    // fused Q/K/V projection + RoPE + mask-folded V: C[2048,3072] = xb @ Wcat^T
    gemm_bt<0, 64><<<dim3(3072 / 128, 2048 / 64), 256, 0, stream>>>(
        xb, Wcat, nullptr, Qb, Kb, VTb, pos, mask, 3072, 2048);

    attn_fused<<<dim3(SEQ / 256, NH), 512, 0, stream>>>(
        Qb, Kb, VTb, mask, ctx);

    // out = ctx @ wo (fp32 direct)
    gemm_bt<1, 64><<<dim3(2048 / 128, 2048 / 64), 256, 0, stream>>>(
        ctx, woT, out, nullptr, nullptr, nullptr, nullptr, nullptr, 2048, 2048);
}

// Round 7
// 206.399 us; speedup vs baseline: 1.3693x; 1.3693x over previous
//
#include <hip/hip_runtime.h>

#define SEQ 2048
#define HID 2048
#define NH  32
#define NKV 8
#define HD  64

typedef _Float16 f16;
typedef __attribute__((ext_vector_type(4))) _Float16 f16x4;
typedef __attribute__((ext_vector_type(8))) _Float16 f16x8;
typedef __attribute__((ext_vector_type(2))) __fp16   h16x2;
typedef __attribute__((ext_vector_type(4))) float    f32x4;

__device__ __forceinline__ f32x4 mfma_16x16x32(f16x8 a, f16x8 b, f32x4 c) {
    return __builtin_amdgcn_mfma_f32_16x16x32_f16(a, b, c, 0, 0, 0);
}

// async global->LDS, 16B per lane. Global address is PER-LANE (gather);
// LDS dest is wave-uniform base + lane*16 (contiguous).
__device__ __forceinline__ void async16(const void* g, void* l) {
    __builtin_amdgcn_global_load_lds(
        (const __attribute__((address_space(1))) void*)g,
        (__attribute__((address_space(3))) void*)l,
        16, 0, 0);
}

// Bijective XCD remap, column-chunked (m204 variant).
__device__ __forceinline__ void xcd_colmap(int& bx, int& by) {
    int gx = gridDim.x, gy = gridDim.y;
    int nwg = gx * gy;
    int orig = by * gx + bx;
    int q = nwg >> 3, r = nwg & 7;
    int xcd = orig & 7, loc = orig >> 3;
    int wg = (xcd < r ? xcd * (q + 1) : r * (q + 1) + (xcd - r) * q) + loc;
    bx = wg / gy;
    by = wg - bx * gy;
}

// ---------------- prep: vectorized transposes + cvt (G13) ----------------------
__global__ void prep_all(const float* __restrict__ x,
                         const float* __restrict__ wq, const float* __restrict__ wk,
                         const float* __restrict__ wv, const float* __restrict__ wo,
                         f16* __restrict__ xb,
                         f16* __restrict__ Wcat, f16* __restrict__ woT) {
    __shared__ float ft[64 * 65];
    int z = blockIdx.z;
    int tid = threadIdx.x;            // 256 threads
    if (z == 4) {                     // cvt: 2048*2048 flat, grid (32,32)
        int base = (blockIdx.y * 32 + blockIdx.x) * 4096 + tid * 8;
#pragma unroll
        for (int i = 0; i < 2; i++) {
            int off = base + i * 2048;
            float4 a = *(const float4*)(x + off);
            float4 b = *(const float4*)(x + off + 4);
            f16x8 o = { (f16)a.x, (f16)a.y, (f16)a.z, (f16)a.w,
                        (f16)b.x, (f16)b.y, (f16)b.z, (f16)b.w };
            *(f16x8*)(xb + off) = o;
        }
        return;
    }
    const float* src; f16* dst; int C;
    if      (z == 0) { src = wq; dst = Wcat;                         C = 2048; }
    else if (z == 1) { src = wk; dst = Wcat + (size_t)2048 * 2048;   C = 512;  }
    else if (z == 2) { src = wv; dst = Wcat + (size_t)2560 * 2048;   C = 512;  }
    else             { src = wo; dst = woT;                          C = 2048; }
    int c0 = blockIdx.x * 64, r0 = blockIdx.y * 64;
    if (c0 >= C) return;
    int c4 = tid & 15;
#pragma unroll
    for (int i = 0; i < 4; i++) {
        int r = (tid >> 4) * 4 + i;
        float4 v = *(const float4*)(src + (size_t)(r0 + r) * C + c0 + c4 * 4);
        *(float4*)(&ft[r * 65 + c4 * 4]) = v;
    }
    __syncthreads();
    int q = tid & 7;
#pragma unroll
    for (int it = 0; it < 2; it++) {
        int jj = (tid >> 3) + it * 32;
        f16x8 v;
#pragma unroll
        for (int e = 0; e < 8; e++)
            v[e] = (f16)ft[(q * 8 + e) * 65 + jj];
        *(f16x8*)(dst + (size_t)(c0 + jj) * 2048 + r0 + q * 8) = v;
    }
}

// ---------------- GEMM: C[M,N] = A[M,K] @ BT[N,K]^T (round-1 known-good) -------
// BM x 128 tile, BK=64, 4 waves 2x2, dbuf staging with XOR-swizzled k-chunks.
// Plain __syncthreads loop (pins/setprio regressed — m141/m190). BM=64 both.
template <int MODE, int BM>
__global__ __launch_bounds__(256)
void gemm_bt(const f16* __restrict__ A, const f16* __restrict__ BT,
             float* __restrict__ Cf, f16* __restrict__ Q, f16* __restrict__ Kk,
             f16* __restrict__ VT, const int* __restrict__ pos,
             const float* __restrict__ mask, int N, int K) {
    constexpr int MI = BM / 32;      // acc rows / af frags per wave
    constexpr int AR = BM / 4;       // A rows staged per wave
    __shared__ f16 As[2][BM * 64];   // [row][k-chunk swizzled]
    __shared__ f16 Bs[2][128 * 64];
    int t = threadIdx.x;
    int w = t >> 6, lane = t & 63, quad = lane >> 4, l15 = lane & 15;
    int wm = w >> 1, wn = w & 1;
    int bx = blockIdx.x, by = blockIdx.y;
    xcd_colmap(bx, by);
    int m0 = by * BM, n0 = bx * 128;
    int sw = l15 & 7;

    int r8 = lane >> 3;            // row within 8-row staging group
    int cc = (lane & 7) ^ r8;      // XOR-swizzled global k-chunk
    const f16* Ag = A  + (size_t)(m0 + w * AR + r8) * K + cc * 8;
    const f16* Bg = BT + (size_t)(n0 + w * 32 + r8) * K + cc * 8;

    f32x4 acc[MI][4] = {};

    // stage tile 0
#pragma unroll
    for (int a = 0; a < AR / 8; a++)
        async16(Ag + (size_t)(8 * a) * K, &As[0][(w * AR + 8 * a) * 64]);
#pragma unroll
    for (int g = 0; g < 4; g++)
        async16(Bg + (size_t)(8 * g) * K, &Bs[0][(w * 32 + 8 * g) * 64]);
    __syncthreads();

    int b = 0;
    for (int kt = 64; kt <= K; kt += 64) {
        if (kt < K) {
#pragma unroll
            for (int a = 0; a < AR / 8; a++)
                async16(Ag + (size_t)(8 * a) * K + kt, &As[b ^ 1][(w * AR + 8 * a) * 64]);
#pragma unroll
            for (int g = 0; g < 4; g++)
                async16(Bg + (size_t)(8 * g) * K + kt, &Bs[b ^ 1][(w * 32 + 8 * g) * 64]);
        }
        f16x8 af[MI][2], bf[4][2];
#pragma unroll
        for (int mi = 0; mi < MI; mi++) {
            int row = wm * (BM / 2) + mi * 16 + l15;
#pragma unroll
            for (int kh = 0; kh < 2; kh++)
                af[mi][kh] = *(const f16x8*)(&As[b][row * 64 + ((kh * 4 + quad) ^ sw) * 8]);
        }
#pragma unroll
        for (int ni = 0; ni < 4; ni++) {
            int row = wn * 64 + ni * 16 + l15;
#pragma unroll
            for (int kh = 0; kh < 2; kh++)
                bf[ni][kh] = *(const f16x8*)(&Bs[b][row * 64 + ((kh * 4 + quad) ^ sw) * 8]);
        }
#pragma unroll
        for (int mi = 0; mi < MI; mi++)
#pragma unroll
            for (int ni = 0; ni < 4; ni++) {
                acc[mi][ni] = mfma_16x16x32(af[mi][0], bf[ni][0], acc[mi][ni]);
                acc[mi][ni] = mfma_16x16x32(af[mi][1], bf[ni][1], acc[mi][ni]);
            }
        __syncthreads();
        b ^= 1;
    }

    int rb  = m0 + wm * (BM / 2) + quad * 4;
    int cbh = n0 + wn * 64;          // 64-aligned: one head per wave column
    if (MODE == 0) {
        if (cbh < (NH + NKV) * HD) {
            bool isQ = cbh < NH * HD;
            f16* dst = isQ ? (Q  + (size_t)(cbh >> 6) * SEQ * HD)
                           : (Kk + (size_t)((cbh - NH * HD) >> 6) * SEQ * HD);
            float scale = isQ ? 0.18033688011112042f : 1.0f;  // (1/8)*log2(e)
            float fr[2];
#pragma unroll
            for (int ni = 0; ni < 2; ni++)
                fr[ni] = __builtin_amdgcn_exp2f(
                    (float)(ni * 16 + l15) * -0.41524101186092029f); // -log2(1e4)/32
#pragma unroll
            for (int mi = 0; mi < MI; mi++)
#pragma unroll
                for (int r = 0; r < 4; r++) {
                    int row = rb + mi * 16 + r;
                    float pv = (float)pos[row];
#pragma unroll
                    for (int ni = 0; ni < 2; ni++) {
                        float sn, cs;
                        __sincosf(pv * fr[ni], &sn, &cs);
                        float x1 = acc[mi][ni][r], x2 = acc[mi][ni + 2][r];
                        int d = ni * 16 + l15;
                        dst[(size_t)row * HD + d]      = (f16)(scale * (x1 * cs - x2 * sn));
                        dst[(size_t)row * HD + d + 32] = (f16)(scale * (x2 * cs + x1 * sn));
                    }
                }
        } else {
            // ---- V^T with mask folded in: VT[c2][s] = v * exp2(mask[s]*log2e).
            const float LOG2E = 1.4426950408889634f;
#pragma unroll
            for (int mi = 0; mi < MI; mi++) {
                float4 mv = *(const float4*)(mask + rb + mi * 16);
                float em[4];
#pragma unroll
                for (int r = 0; r < 4; r++)
                    em[r] = __builtin_amdgcn_exp2f((&mv.x)[r] * LOG2E);
#pragma unroll
                for (int ni = 0; ni < 4; ni++) {
                    int c2 = cbh - (NH + NKV) * HD + ni * 16 + l15;
                    f16x4 v4;
                    ((h16x2*)&v4)[0] = __builtin_amdgcn_cvt_pkrtz(
                        acc[mi][ni][0] * em[0], acc[mi][ni][1] * em[1]);
                    ((h16x2*)&v4)[1] = __builtin_amdgcn_cvt_pkrtz(
                        acc[mi][ni][2] * em[2], acc[mi][ni][3] * em[3]);
                    *(f16x4*)(VT + (size_t)c2 * SEQ + rb + mi * 16) = v4;
                }
            }
        }
    } else {
#pragma unroll
        for (int mi = 0; mi < MI; mi++)
#pragma unroll
            for (int ni = 0; ni < 4; ni++)
#pragma unroll
                for (int r = 0; r < 4; r++)
                    Cf[(size_t)(rb + mi * 16 + r) * N + cbh + ni * 16 + l15] =
                        acc[mi][ni][r];
    }
}

// ---------------- fused flash attention: producer/consumer, 4x64q consumers ----
// grid (SEQ/256, NH) = 256 blocks x 512 threads (1 block/CU).
// Waves 0-3 = PRODUCERS: stage K (waves 0-1, permuted rows g(), per-async16
// key offsets {0,16,4,20} — round-2-verified map) and V^T (waves 2-3, rows
// {0,8,16,24}) into the tri-buffer. Waves 4-7 = CONSUMERS: 64 q-rows each
// (4 q-groups) — the shared K/V tile is read 4x per tile instead of 8x,
// halving the LDS-read stream (the measured binding pipe: 8x18 b128 x 12cy
// = 1730cy/tile vs ~1050 now). Total MFMA unchanged. Tri-buffer + ONE
// barrier per tile; producers count vmcnt(4), consumers just barrier
// (barrier counts match exactly). Mask folded into V; l via em-MFMA;
// normalize in-register, write ctx directly. LDS = 52 KB.
__global__ __launch_bounds__(512, 2)
void attn_fused(const f16* __restrict__ Qb, const f16* __restrict__ Kb,
                const f16* __restrict__ VTb, const float* __restrict__ mask,
                f16* __restrict__ ctx) {
    __shared__ f16 Ks[3][64 * 64];
    __shared__ f16 Vs[3][64 * 64];
    __shared__ f16 Em[SEQ];

    int t = threadIdx.x, w = t >> 6, lane = t & 63, quad = lane >> 4, l15 = lane & 15;
    int h = blockIdx.y, kvh = h >> 2;
    const f16* Qh = Qb  + (size_t)h   * SEQ * HD;
    const f16* Kh = Kb  + (size_t)kvh * SEQ * HD;
    const f16* Vh = VTb + (size_t)kvh * HD * SEQ;
    int sw = l15 & 7;
    const float LOG2E = 1.4426950408889634f;
    bool isProd = w < 4;

    // ---- producer staging addresses (round-2-verified maps) ----
    int r8 = lane >> 3;
    int cc = (lane & 7) ^ r8;
    const f16 *kv0 = nullptr, *kv1 = nullptr, *kv2 = nullptr, *kv3 = nullptr;
    long adv = 0;
    int lbase = 0;
    bool isK = w < 2;
    if (isProd) {
        if (isK) {
            // LDS K row rr = w*32 + 8a + r8 holds global key
            // g(rr) = w*32 + {0,16,4,20}[a] + 8*(r8>>2) + (r8&3)
            const f16* bl = Kh + (size_t)(w * 32 + 8 * (r8 >> 2) + (r8 & 3)) * HD
                               + cc * 8;
            kv0 = bl;                   kv1 = bl + (size_t)16 * HD;
            kv2 = bl + (size_t)4 * HD;  kv3 = bl + (size_t)20 * HD;
            adv = (long)64 * HD;
            lbase = w * 32 * 64;
        } else {
            int ws2 = w - 2;
            const f16* bl = Vh + (size_t)(ws2 * 32 + r8) * SEQ + cc * 8;
            kv0 = bl;                    kv1 = bl + (size_t)8 * SEQ;
            kv2 = bl + (size_t)16 * SEQ; kv3 = bl + (size_t)24 * SEQ;
            adv = 64;
            lbase = ws2 * 32 * 64;
        }
    }

    // rotating tri-buffer: *A = compute (tile t), *B = stage (tile t+1)
    f16 *kA = &Ks[0][0], *kB = &Ks[1][0], *kC3 = &Ks[2][0];
    f16 *vA = &Vs[0][0], *vB = &Vs[1][0], *vC3 = &Vs[2][0];

    if (isProd) {   // stage tile 0 into buffer A
        f16* dst = (isK ? kA : vA) + lbase;
        async16(kv0, dst);        async16(kv1, dst + 512);
        async16(kv2, dst + 1024); async16(kv3, dst + 1536);
    }

    // ---- stage em = exp2(mask*log2e) for full SEQ (all 512 threads) ----
    {
        int idx = t * 4;
        float4 mv = *(const float4*)(mask + idx);
        f16x4 e;
        ((h16x2*)&e)[0] = __builtin_amdgcn_cvt_pkrtz(
            __builtin_amdgcn_exp2f(mv.x * LOG2E), __builtin_amdgcn_exp2f(mv.y * LOG2E));
        ((h16x2*)&e)[1] = __builtin_amdgcn_cvt_pkrtz(
            __builtin_amdgcn_exp2f(mv.z * LOG2E), __builtin_amdgcn_exp2f(mv.w * LOG2E));
        *(f16x4*)(&Em[idx]) = e;
    }

    // ---- consumer state: 64 q-rows per wave (4 q-groups) ----
    int cw = w - 4;
    int qbase = blockIdx.x * 256 + cw * 64;
    f16x8 bq[4][2];
    if (!isProd) {
#pragma unroll
        for (int qg = 0; qg < 4; qg++)
#pragma unroll
            for (int ks = 0; ks < 2; ks++)
                bq[qg][ks] = *(const f16x8*)(Qh
                    + (size_t)(qbase + qg * 16 + l15) * HD + ks * 32 + quad * 8);
    }

    f32x4 o[4][4] = {};          // O^T: [d-tile][q-group]
    f32x4 ol[4]   = {};          // l accumulator (all rows identical)

    int c0 = (quad ^ sw) * 8, c1 = ((4 | quad) ^ sw) * 8;

    // Em ds_writes drained before the first barrier publishes them
    // (async16 tile-0 loads remain in flight — lgkmcnt only counts LDS ops)
    asm volatile("s_waitcnt lgkmcnt(0)" ::: "memory");

    const int NT = SEQ / 64;
    for (int ktl = 0; ktl < NT; ktl++) {
        if (isProd) {
            if (ktl + 1 < NT) {
                kv0 += adv; kv1 += adv; kv2 += adv; kv3 += adv;
                f16* dst = (isK ? kB : vB) + lbase;
                async16(kv0, dst);        async16(kv1, dst + 512);
                async16(kv2, dst + 1024); async16(kv3, dst + 1536);
                // my tile-t loads are oldest; only the 4 t+1 loads may remain
                asm volatile("s_waitcnt vmcnt(4)" ::: "memory");
            } else {
                asm volatile("s_waitcnt vmcnt(0)" ::: "memory");
            }
        }
        __builtin_amdgcn_sched_barrier(0);
        __builtin_amdgcn_s_barrier();            // tile-t loads landed for all
        __builtin_amdgcn_sched_barrier(0);       // pin: no ds_read hoists above

        if (!isProd) {
            const f16* Kb_ = kA;
            const f16* Vb_ = vA;

            // ---- S^T = K @ Q^T (keys in permuted order) ----
            f32x4 st[4][4] = {};
            __builtin_amdgcn_s_setprio(1);
#pragma unroll
            for (int ni = 0; ni < 4; ni++) {
                const f16* kr = Kb_ + (ni * 16 + l15) * 64;
                f16x8 ak0 = *(const f16x8*)(kr + c0);
                f16x8 ak1 = *(const f16x8*)(kr + c1);
#pragma unroll
                for (int qg = 0; qg < 4; qg++) {
                    st[ni][qg] = mfma_16x16x32(ak0, bq[qg][0], st[ni][qg]);
                    st[ni][qg] = mfma_16x16x32(ak1, bq[qg][1], st[ni][qg]);
                }
            }
            __builtin_amdgcn_s_setprio(0);
            // ---- p = exp2(s); pack via cvt_pkrtz ----
            f16x8 pb[4][2];   // [qg][ks]
#pragma unroll
            for (int ni = 0; ni < 4; ni++)
#pragma unroll
                for (int qg = 0; qg < 4; qg++) {
                    h16x2 lo = __builtin_amdgcn_cvt_pkrtz(
                        __builtin_amdgcn_exp2f(st[ni][qg][0]),
                        __builtin_amdgcn_exp2f(st[ni][qg][1]));
                    h16x2 hi = __builtin_amdgcn_cvt_pkrtz(
                        __builtin_amdgcn_exp2f(st[ni][qg][2]),
                        __builtin_amdgcn_exp2f(st[ni][qg][3]));
                    ((h16x2*)&pb[qg][ni >> 1])[(ni & 1) * 2]     = lo;
                    ((h16x2*)&pb[qg][ni >> 1])[(ni & 1) * 2 + 1] = hi;
                }
            // ---- l += em-row @ P ----
            f16x8 em0 = *(const f16x8*)(&Em[ktl * 64 + quad * 8]);
            f16x8 em1 = *(const f16x8*)(&Em[ktl * 64 + 32 + quad * 8]);
            __builtin_amdgcn_s_setprio(1);
#pragma unroll
            for (int qg = 0; qg < 4; qg++) {
                ol[qg] = mfma_16x16x32(em0, pb[qg][0], ol[qg]);
                ol[qg] = mfma_16x16x32(em1, pb[qg][1], ol[qg]);
            }
            // ---- O^T += V^T @ P ----
#pragma unroll
            for (int dt = 0; dt < 4; dt++) {
                const f16* vr = Vb_ + (dt * 16 + l15) * 64;
                f16x8 av0 = *(const f16x8*)(vr + c0);
                f16x8 av1 = *(const f16x8*)(vr + c1);
#pragma unroll
                for (int qg = 0; qg < 4; qg++) {
                    o[dt][qg] = mfma_16x16x32(av0, pb[qg][0], o[dt][qg]);
                    o[dt][qg] = mfma_16x16x32(av1, pb[qg][1], o[dt][qg]);
                }
            }
            __builtin_amdgcn_s_setprio(0);
        }
        // rotate buffers: compute<-stage, stage<-free, free<-old compute
        f16* tk = kA; kA = kB; kB = kC3; kC3 = tk;
        f16* tv = vA; vA = vB; vB = vC3; vC3 = tv;
    }

    // ---- consumers: normalize in-register, write ctx directly ----
    if (!isProd) {
        float inv[4];
#pragma unroll
        for (int qg = 0; qg < 4; qg++) inv[qg] = 1.0f / ol[qg][0];
#pragma unroll
        for (int dt = 0; dt < 4; dt++)
#pragma unroll
            for (int qg = 0; qg < 4; qg++) {
                f16x4 v4;
                ((h16x2*)&v4)[0] = __builtin_amdgcn_cvt_pkrtz(
                    o[dt][qg][0] * inv[qg], o[dt][qg][1] * inv[qg]);
                ((h16x2*)&v4)[1] = __builtin_amdgcn_cvt_pkrtz(
                    o[dt][qg][2] * inv[qg], o[dt][qg][3] * inv[qg]);
                *(f16x4*)(ctx + (size_t)(qbase + qg * 16 + l15) * (NH * HD)
                              + h * HD + dt * 16 + quad * 4) = v4;
            }
    }
}

// ---------------- launch ----------------
extern "C" void kernel_launch(void* const* d_in, const int* in_sizes, int n_in,
                              void* d_out, int out_size, void* d_ws, size_t ws_size,
                              hipStream_t stream) {
    const float* x    = (const float*)d_in[0];
    const float* mask = (const float*)d_in[1];
    const int*   pos  = (const int*)  d_in[2];
    const float* wq   = (const float*)d_in[3];
    const float* wk   = (const float*)d_in[4];
    const float* wv   = (const float*)d_in[5];
    const float* wo   = (const float*)d_in[6];
    float* out = (float*)d_out;

    char* ws = (char*)d_ws;
    // phase 1-2: xb [0,8M), Wcat [8,20M), woT [20,28M), Qb [28,36M),
    //            Kb [36,38M), VTb [38,40M)
    // phase 3:   ctx [0,8M) (xb dead after gemm0)
    // phase 4:   gemm1 reads ctx + woT
    f16*   xb    = (f16*)(ws);
    f16*   Wcat  = (f16*)(ws + ((size_t)8  << 20));
    f16*   woT   = (f16*)(ws + ((size_t)20 << 20));
    f16*   Qb    = (f16*)(ws + ((size_t)28 << 20));
    f16*   Kb    = (f16*)(ws + ((size_t)36 << 20));
    f16*   VTb   = (f16*)(ws + ((size_t)38 << 20));
    f16*   ctx   = (f16*)(ws);

    prep_all<<<dim3(32, 32, 5), 256, 0, stream>>>(
        x, wq, wk, wv, wo, xb, Wcat, woT);

    // fused Q/K/V projection + RoPE + mask-folded V: C[2048,3072] = xb @ Wcat^T
    gemm_bt<0, 64><<<dim3(3072 / 128, 2048 / 64), 256, 0, stream>>>(
        xb, Wcat, nullptr, Qb, Kb, VTb, pos, mask, 3072, 2048);

    attn_fused<<<dim3(SEQ / 256, NH), 512, 0, stream>>>(
        Qb, Kb, VTb, mask, ctx);

    // out = ctx @ wo (fp32 direct)
    gemm_bt<1, 64><<<dim3(2048 / 128, 2048 / 64), 256, 0, stream>>>(
        ctx, woT, out, nullptr, nullptr, nullptr, nullptr, nullptr, 2048, 2048);
}

// Round 8
// 204.567 us; speedup vs baseline: 1.3816x; 1.0090x over previous
//
#include <hip/hip_runtime.h>

#define SEQ 2048
#define HID 2048
#define NH  32
#define NKV 8
#define HD  64

typedef _Float16 f16;
typedef __attribute__((ext_vector_type(4))) _Float16 f16x4;
typedef __attribute__((ext_vector_type(8))) _Float16 f16x8;
typedef __attribute__((ext_vector_type(2))) __fp16   h16x2;
typedef __attribute__((ext_vector_type(4))) float    f32x4;

__device__ __forceinline__ f32x4 mfma_16x16x32(f16x8 a, f16x8 b, f32x4 c) {
    return __builtin_amdgcn_mfma_f32_16x16x32_f16(a, b, c, 0, 0, 0);
}

// async global->LDS, 16B per lane. Global address is PER-LANE (gather);
// LDS dest is wave-uniform base + lane*16 (contiguous).
__device__ __forceinline__ void async16(const void* g, void* l) {
    __builtin_amdgcn_global_load_lds(
        (const __attribute__((address_space(1))) void*)g,
        (__attribute__((address_space(3))) void*)l,
        16, 0, 0);
}

// Bijective XCD remap, column-chunked (m204 variant).
__device__ __forceinline__ void xcd_colmap(int& bx, int& by) {
    int gx = gridDim.x, gy = gridDim.y;
    int nwg = gx * gy;
    int orig = by * gx + bx;
    int q = nwg >> 3, r = nwg & 7;
    int xcd = orig & 7, loc = orig >> 3;
    int wg = (xcd < r ? xcd * (q + 1) : r * (q + 1) + (xcd - r) * q) + loc;
    bx = wg / gy;
    by = wg - bx * gy;
}

// ---------------- prep: vectorized transposes + cvt (G13) ----------------------
__global__ void prep_all(const float* __restrict__ x,
                         const float* __restrict__ wq, const float* __restrict__ wk,
                         const float* __restrict__ wv, const float* __restrict__ wo,
                         f16* __restrict__ xb,
                         f16* __restrict__ Wcat, f16* __restrict__ woT) {
    __shared__ float ft[64 * 65];
    int z = blockIdx.z;
    int tid = threadIdx.x;            // 256 threads
    if (z == 4) {                     // cvt: 2048*2048 flat, grid (32,32)
        int base = (blockIdx.y * 32 + blockIdx.x) * 4096 + tid * 8;
#pragma unroll
        for (int i = 0; i < 2; i++) {
            int off = base + i * 2048;
            float4 a = *(const float4*)(x + off);
            float4 b = *(const float4*)(x + off + 4);
            f16x8 o = { (f16)a.x, (f16)a.y, (f16)a.z, (f16)a.w,
                        (f16)b.x, (f16)b.y, (f16)b.z, (f16)b.w };
            *(f16x8*)(xb + off) = o;
        }
        return;
    }
    const float* src; f16* dst; int C;
    if      (z == 0) { src = wq; dst = Wcat;                         C = 2048; }
    else if (z == 1) { src = wk; dst = Wcat + (size_t)2048 * 2048;   C = 512;  }
    else if (z == 2) { src = wv; dst = Wcat + (size_t)2560 * 2048;   C = 512;  }
    else             { src = wo; dst = woT;                          C = 2048; }
    int c0 = blockIdx.x * 64, r0 = blockIdx.y * 64;
    if (c0 >= C) return;
    int c4 = tid & 15;
#pragma unroll
    for (int i = 0; i < 4; i++) {
        int r = (tid >> 4) * 4 + i;
        float4 v = *(const float4*)(src + (size_t)(r0 + r) * C + c0 + c4 * 4);
        *(float4*)(&ft[r * 65 + c4 * 4]) = v;
    }
    __syncthreads();
    int q = tid & 7;
#pragma unroll
    for (int it = 0; it < 2; it++) {
        int jj = (tid >> 3) + it * 32;
        f16x8 v;
#pragma unroll
        for (int e = 0; e < 8; e++)
            v[e] = (f16)ft[(q * 8 + e) * 65 + jj];
        *(f16x8*)(dst + (size_t)(c0 + jj) * 2048 + r0 + q * 8) = v;
    }
}

// ---------------- GEMM: C[M,N] = A[M,K] @ BT[N,K]^T (round-1 known-good) -------
// BM x 128 tile, BK=64, 4 waves 2x2, dbuf staging with XOR-swizzled k-chunks.
// Plain __syncthreads loop (pins/setprio regressed — m141/m190). BM=64 both.
template <int MODE, int BM>
__global__ __launch_bounds__(256)
void gemm_bt(const f16* __restrict__ A, const f16* __restrict__ BT,
             float* __restrict__ Cf, f16* __restrict__ Q, f16* __restrict__ Kk,
             f16* __restrict__ VT, const int* __restrict__ pos,
             const float* __restrict__ mask, int N, int K) {
    constexpr int MI = BM / 32;      // acc rows / af frags per wave
    constexpr int AR = BM / 4;       // A rows staged per wave
    __shared__ f16 As[2][BM * 64];   // [row][k-chunk swizzled]
    __shared__ f16 Bs[2][128 * 64];
    int t = threadIdx.x;
    int w = t >> 6, lane = t & 63, quad = lane >> 4, l15 = lane & 15;
    int wm = w >> 1, wn = w & 1;
    int bx = blockIdx.x, by = blockIdx.y;
    xcd_colmap(bx, by);
    int m0 = by * BM, n0 = bx * 128;
    int sw = l15 & 7;

    int r8 = lane >> 3;            // row within 8-row staging group
    int cc = (lane & 7) ^ r8;      // XOR-swizzled global k-chunk
    const f16* Ag = A  + (size_t)(m0 + w * AR + r8) * K + cc * 8;
    const f16* Bg = BT + (size_t)(n0 + w * 32 + r8) * K + cc * 8;

    f32x4 acc[MI][4] = {};

    // stage tile 0
#pragma unroll
    for (int a = 0; a < AR / 8; a++)
        async16(Ag + (size_t)(8 * a) * K, &As[0][(w * AR + 8 * a) * 64]);
#pragma unroll
    for (int g = 0; g < 4; g++)
        async16(Bg + (size_t)(8 * g) * K, &Bs[0][(w * 32 + 8 * g) * 64]);
    __syncthreads();

    int b = 0;
    for (int kt = 64; kt <= K; kt += 64) {
        if (kt < K) {
#pragma unroll
            for (int a = 0; a < AR / 8; a++)
                async16(Ag + (size_t)(8 * a) * K + kt, &As[b ^ 1][(w * AR + 8 * a) * 64]);
#pragma unroll
            for (int g = 0; g < 4; g++)
                async16(Bg + (size_t)(8 * g) * K + kt, &Bs[b ^ 1][(w * 32 + 8 * g) * 64]);
        }
        f16x8 af[MI][2], bf[4][2];
#pragma unroll
        for (int mi = 0; mi < MI; mi++) {
            int row = wm * (BM / 2) + mi * 16 + l15;
#pragma unroll
            for (int kh = 0; kh < 2; kh++)
                af[mi][kh] = *(const f16x8*)(&As[b][row * 64 + ((kh * 4 + quad) ^ sw) * 8]);
        }
#pragma unroll
        for (int ni = 0; ni < 4; ni++) {
            int row = wn * 64 + ni * 16 + l15;
#pragma unroll
            for (int kh = 0; kh < 2; kh++)
                bf[ni][kh] = *(const f16x8*)(&Bs[b][row * 64 + ((kh * 4 + quad) ^ sw) * 8]);
        }
#pragma unroll
        for (int mi = 0; mi < MI; mi++)
#pragma unroll
            for (int ni = 0; ni < 4; ni++) {
                acc[mi][ni] = mfma_16x16x32(af[mi][0], bf[ni][0], acc[mi][ni]);
                acc[mi][ni] = mfma_16x16x32(af[mi][1], bf[ni][1], acc[mi][ni]);
            }
        __syncthreads();
        b ^= 1;
    }

    int rb  = m0 + wm * (BM / 2) + quad * 4;
    int cbh = n0 + wn * 64;          // 64-aligned: one head per wave column
    if (MODE == 0) {
        if (cbh < (NH + NKV) * HD) {
            bool isQ = cbh < NH * HD;
            f16* dst = isQ ? (Q  + (size_t)(cbh >> 6) * SEQ * HD)
                           : (Kk + (size_t)((cbh - NH * HD) >> 6) * SEQ * HD);
            float scale = isQ ? 0.18033688011112042f : 1.0f;  // (1/8)*log2(e)
            float fr[2];
#pragma unroll
            for (int ni = 0; ni < 2; ni++)
                fr[ni] = __builtin_amdgcn_exp2f(
                    (float)(ni * 16 + l15) * -0.41524101186092029f); // -log2(1e4)/32
#pragma unroll
            for (int mi = 0; mi < MI; mi++)
#pragma unroll
                for (int r = 0; r < 4; r++) {
                    int row = rb + mi * 16 + r;
                    float pv = (float)pos[row];
#pragma unroll
                    for (int ni = 0; ni < 2; ni++) {
                        float sn, cs;
                        __sincosf(pv * fr[ni], &sn, &cs);
                        float x1 = acc[mi][ni][r], x2 = acc[mi][ni + 2][r];
                        int d = ni * 16 + l15;
                        dst[(size_t)row * HD + d]      = (f16)(scale * (x1 * cs - x2 * sn));
                        dst[(size_t)row * HD + d + 32] = (f16)(scale * (x2 * cs + x1 * sn));
                    }
                }
        } else {
            // ---- V^T with mask folded in: VT[c2][s] = v * exp2(mask[s]*log2e).
            const float LOG2E = 1.4426950408889634f;
#pragma unroll
            for (int mi = 0; mi < MI; mi++) {
                float4 mv = *(const float4*)(mask + rb + mi * 16);
                float em[4];
#pragma unroll
                for (int r = 0; r < 4; r++)
                    em[r] = __builtin_amdgcn_exp2f((&mv.x)[r] * LOG2E);
#pragma unroll
                for (int ni = 0; ni < 4; ni++) {
                    int c2 = cbh - (NH + NKV) * HD + ni * 16 + l15;
                    f16x4 v4;
                    ((h16x2*)&v4)[0] = __builtin_amdgcn_cvt_pkrtz(
                        acc[mi][ni][0] * em[0], acc[mi][ni][1] * em[1]);
                    ((h16x2*)&v4)[1] = __builtin_amdgcn_cvt_pkrtz(
                        acc[mi][ni][2] * em[2], acc[mi][ni][3] * em[3]);
                    *(f16x4*)(VT + (size_t)c2 * SEQ + rb + mi * 16) = v4;
                }
            }
        }
    } else {
#pragma unroll
        for (int mi = 0; mi < MI; mi++)
#pragma unroll
            for (int ni = 0; ni < 4; ni++)
#pragma unroll
                for (int r = 0; r < 4; r++)
                    Cf[(size_t)(rb + mi * 16 + r) * N + cbh + ni * 16 + l15] =
                        acc[mi][ni][r];
    }
}

// ---------------- fused flash attention: deferred-PV software pipeline ---------
// grid (SEQ/256, NH) = 256 blocks x 512 threads. Round-5 symmetric 8-wave
// staging (waves 0-3 K permuted-rows, waves 4-7 V^T; 2 async16/wave/tile),
// QUAD ring buffer, ONE barrier per tile. At iter t: QK reads buf[t&3],
// PV(t-1) reads buf[(t-1)&3] with pbPrev (P packed LAST iteration), staging
// writes buf[(t+1)&3] (overwrites tile t-3: reads completed 2 barriers ago
// — race-checked; all concurrently-accessed slots differ mod 4). Deferring
// PV one tile removes the serial QK->exp2->PV chain from the critical path:
// the exp2/pack result is not consumed until the NEXT iteration, so the
// MFMA pipe sees QK(t)+PV(t-1) = 36 back-to-back independent MFMAs.
// vmcnt(2) = correct count for 2 loads/wave (round-5's vmcnt(4) was a
// no-op that worked only because tile time >> load latency). LDS = 68 KB.
__global__ __launch_bounds__(512)
void attn_fused(const f16* __restrict__ Qb, const f16* __restrict__ Kb,
                const f16* __restrict__ VTb, const float* __restrict__ mask,
                f16* __restrict__ ctx) {
    __shared__ f16 Ks[4][64 * 64];
    __shared__ f16 Vs[4][64 * 64];
    __shared__ f16 Em[SEQ];

    int t = threadIdx.x, w = t >> 6, lane = t & 63, quad = lane >> 4, l15 = lane & 15;
    int h = blockIdx.y, kvh = h >> 2;
    int qbase = blockIdx.x * 256 + w * 32;
    const f16* Qh = Qb  + (size_t)h   * SEQ * HD;
    const f16* Kh = Kb  + (size_t)kvh * SEQ * HD;
    const f16* Vh = VTb + (size_t)kvh * HD * SEQ;
    int sw = l15 & 7;
    const float LOG2E = 1.4426950408889634f;

    // ---- staging: wave role. K waves use permuted rows (g(rr)=k_eff). ----
    int r8 = lane >> 3;
    int cc = (lane & 7) ^ r8;
    bool isK = w < 4;
    int ws = isK ? w : (w - 4);
    const f16* g0;
    long gstep;
    if (isK) {
        int gk = 32 * (ws >> 1) + 4 * (ws & 1) + 8 * (r8 >> 2) + (r8 & 3);
        g0 = Kh + (size_t)gk * HD + cc * 8;
        gstep = (long)16 * HD;       // second async16: keys g+16
    } else {
        g0 = Vh + (size_t)(ws * 16 + r8) * SEQ + cc * 8;
        gstep = (long)8 * SEQ;       // second async16: rows +8
    }
    const f16* g1 = g0 + gstep;
    long adv = isK ? (long)64 * HD : 64;
    int lr0 = ws * 16 * 64, lr1 = lr0 + 8 * 64;

    {   // stage tile 0 into slot 0
        f16* dst = (isK ? &Ks[0][0] : &Vs[0][0]);
        async16(g0, dst + lr0);
        async16(g1, dst + lr1);
    }

    // ---- stage em = exp2(mask*log2e) for full SEQ (one f16x4 per thread) ----
    {
        int idx = t * 4;
        float4 mv = *(const float4*)(mask + idx);
        f16x4 e;
        ((h16x2*)&e)[0] = __builtin_amdgcn_cvt_pkrtz(
            __builtin_amdgcn_exp2f(mv.x * LOG2E), __builtin_amdgcn_exp2f(mv.y * LOG2E));
        ((h16x2*)&e)[1] = __builtin_amdgcn_cvt_pkrtz(
            __builtin_amdgcn_exp2f(mv.z * LOG2E), __builtin_amdgcn_exp2f(mv.w * LOG2E));
        *(f16x4*)(&Em[idx]) = e;
    }

    // ---- Q fragments (persistent): B-operand of S^T, n = q ----
    f16x8 bq[2][2];
#pragma unroll
    for (int qg = 0; qg < 2; qg++)
#pragma unroll
        for (int ks = 0; ks < 2; ks++)
            bq[qg][ks] = *(const f16x8*)(Qh + (size_t)(qbase + qg * 16 + l15) * HD
                                            + ks * 32 + quad * 8);

    f32x4 o[4][2] = {};          // O^T: [d-tile][q-group]
    f32x4 ol[2]   = {};          // l accumulator (all rows identical)
    f16x8 pbP[2][2];             // PREVIOUS tile's packed P  [qg][ks]

    int c0 = (quad ^ sw) * 8, c1 = ((4 | quad) ^ sw) * 8;

    // Em ds_writes drained before the first barrier publishes them
    asm volatile("s_waitcnt lgkmcnt(0)" ::: "memory");

    const int NT = SEQ / 64;
    for (int ktl = 0; ktl < NT; ktl++) {
        if (ktl + 1 < NT) {
            g0 += adv; g1 += adv;
            f16* dst = (isK ? &Ks[(ktl + 1) & 3][0] : &Vs[(ktl + 1) & 3][0]);
            async16(g0, dst + lr0);
            async16(g1, dst + lr1);
            // my tile-t loads are oldest; only the 2 t+1 loads may remain
            asm volatile("s_waitcnt vmcnt(2)" ::: "memory");
        } else {
            asm volatile("s_waitcnt vmcnt(0)" ::: "memory");
        }
        __builtin_amdgcn_sched_barrier(0);
        __builtin_amdgcn_s_barrier();            // tile-t loads landed for all
        __builtin_amdgcn_sched_barrier(0);       // pin: no ds_read hoists above

        const f16* Kb_ = &Ks[ktl & 3][0];

        // ---- S^T = K @ Q^T (keys in permuted order) ----
        f32x4 st[4][2] = {};
        __builtin_amdgcn_s_setprio(1);
#pragma unroll
        for (int ni = 0; ni < 4; ni++) {
            const f16* kr = Kb_ + (ni * 16 + l15) * 64;
            f16x8 ak0 = *(const f16x8*)(kr + c0);
            f16x8 ak1 = *(const f16x8*)(kr + c1);
#pragma unroll
            for (int qg = 0; qg < 2; qg++) {
                st[ni][qg] = mfma_16x16x32(ak0, bq[qg][0], st[ni][qg]);
                st[ni][qg] = mfma_16x16x32(ak1, bq[qg][1], st[ni][qg]);
            }
        }
        __builtin_amdgcn_s_setprio(0);

        // ---- deferred PV: l += em @ P(t-1);  O^T += V^T(t-1) @ P(t-1) ----
        if (ktl > 0) {
            const f16* Vb_ = &Vs[(ktl - 1) & 3][0];
            f16x8 em0 = *(const f16x8*)(&Em[(ktl - 1) * 64 + quad * 8]);
            f16x8 em1 = *(const f16x8*)(&Em[(ktl - 1) * 64 + 32 + quad * 8]);
            __builtin_amdgcn_s_setprio(1);
#pragma unroll
            for (int qg = 0; qg < 2; qg++) {
                ol[qg] = mfma_16x16x32(em0, pbP[qg][0], ol[qg]);
                ol[qg] = mfma_16x16x32(em1, pbP[qg][1], ol[qg]);
            }
#pragma unroll
            for (int dt = 0; dt < 4; dt++) {
                const f16* vr = Vb_ + (dt * 16 + l15) * 64;
                f16x8 av0 = *(const f16x8*)(vr + c0);
                f16x8 av1 = *(const f16x8*)(vr + c1);
#pragma unroll
                for (int qg = 0; qg < 2; qg++) {
                    o[dt][qg] = mfma_16x16x32(av0, pbP[qg][0], o[dt][qg]);
                    o[dt][qg] = mfma_16x16x32(av1, pbP[qg][1], o[dt][qg]);
                }
            }
            __builtin_amdgcn_s_setprio(0);
        }

        // ---- p = exp2(s), pack into pbP for NEXT iteration ----
        // (WAR on pbP: PV above read it first — register dependency holds)
#pragma unroll
        for (int ni = 0; ni < 4; ni++)
#pragma unroll
            for (int qg = 0; qg < 2; qg++) {
                h16x2 lo = __builtin_amdgcn_cvt_pkrtz(
                    __builtin_amdgcn_exp2f(st[ni][qg][0]),
                    __builtin_amdgcn_exp2f(st[ni][qg][1]));
                h16x2 hi = __builtin_amdgcn_cvt_pkrtz(
                    __builtin_amdgcn_exp2f(st[ni][qg][2]),
                    __builtin_amdgcn_exp2f(st[ni][qg][3]));
                ((h16x2*)&pbP[qg][ni >> 1])[(ni & 1) * 2]     = lo;
                ((h16x2*)&pbP[qg][ni >> 1])[(ni & 1) * 2 + 1] = hi;
            }
    }

    // ---- tail: PV for the last tile (NT-1) ----
    {
        const f16* Vb_ = &Vs[(NT - 1) & 3][0];
        f16x8 em0 = *(const f16x8*)(&Em[(NT - 1) * 64 + quad * 8]);
        f16x8 em1 = *(const f16x8*)(&Em[(NT - 1) * 64 + 32 + quad * 8]);
#pragma unroll
        for (int qg = 0; qg < 2; qg++) {
            ol[qg] = mfma_16x16x32(em0, pbP[qg][0], ol[qg]);
            ol[qg] = mfma_16x16x32(em1, pbP[qg][1], ol[qg]);
        }
#pragma unroll
        for (int dt = 0; dt < 4; dt++) {
            const f16* vr = Vb_ + (dt * 16 + l15) * 64;
            f16x8 av0 = *(const f16x8*)(vr + c0);
            f16x8 av1 = *(const f16x8*)(vr + c1);
#pragma unroll
            for (int qg = 0; qg < 2; qg++) {
                o[dt][qg] = mfma_16x16x32(av0, pbP[qg][0], o[dt][qg]);
                o[dt][qg] = mfma_16x16x32(av1, pbP[qg][1], o[dt][qg]);
            }
        }
    }

    // ---- normalize in-register, write ctx[row][h*64+d] directly ----
    float inv[2] = { 1.0f / ol[0][0], 1.0f / ol[1][0] };
#pragma unroll
    for (int dt = 0; dt < 4; dt++)
#pragma unroll
        for (int qg = 0; qg < 2; qg++) {
            f16x4 v4;
            ((h16x2*)&v4)[0] = __builtin_amdgcn_cvt_pkrtz(
                o[dt][qg][0] * inv[qg], o[dt][qg][1] * inv[qg]);
            ((h16x2*)&v4)[1] = __builtin_amdgcn_cvt_pkrtz(
                o[dt][qg][2] * inv[qg], o[dt][qg][3] * inv[qg]);
            *(f16x4*)(ctx + (size_t)(qbase + qg * 16 + l15) * (NH * HD)
                          + h * HD + dt * 16 + quad * 4) = v4;
        }
}

// ---------------- launch ----------------
extern "C" void kernel_launch(void* const* d_in, const int* in_sizes, int n_in,
                              void* d_out, int out_size, void* d_ws, size_t ws_size,
                              hipStream_t stream) {
    const float* x    = (const float*)d_in[0];
    const float* mask = (const float*)d_in[1];
    const int*   pos  = (const int*)  d_in[2];
    const float* wq   = (const float*)d_in[3];
    const float* wk   = (const float*)d_in[4];
    const float* wv   = (const float*)d_in[5];
    const float* wo   = (const float*)d_in[6];
    float* out = (float*)d_out;

    char* ws = (char*)d_ws;
    // phase 1-2: xb [0,8M), Wcat [8,20M), woT [20,28M), Qb [28,36M),
    //            Kb [36,38M), VTb [38,40M)
    // phase 3:   ctx [0,8M) (xb dead after gemm0)
    // phase 4:   gemm1 reads ctx + woT
    f16*   xb    = (f16*)(ws);
    f16*   Wcat  = (f16*)(ws + ((size_t)8  << 20));
    f16*   woT   = (f16*)(ws + ((size_t)20 << 20));
    f16*   Qb    = (f16*)(ws + ((size_t)28 << 20));
    f16*   Kb    = (f16*)(ws + ((size_t)36 << 20));
    f16*   VTb   = (f16*)(ws + ((size_t)38 << 20));
    f16*   ctx   = (f16*)(ws);

    prep_all<<<dim3(32, 32, 5), 256, 0, stream>>>(
        x, wq, wk, wv, wo, xb, Wcat, woT);

    // fused Q/K/V projection + RoPE + mask-folded V: C[2048,3072] = xb @ Wcat^T
    gemm_bt<0, 64><<<dim3(3072 / 128, 2048 / 64), 256, 0, stream>>>(
        xb, Wcat, nullptr, Qb, Kb, VTb, pos, mask, 3072, 2048);

    attn_fused<<<dim3(SEQ / 256, NH), 512, 0, stream>>>(
        Qb, Kb, VTb, mask, ctx);

    // out = ctx @ wo (fp32 direct)
    gemm_bt<1, 64><<<dim3(2048 / 128, 2048 / 64), 256, 0, stream>>>(
        ctx, woT, out, nullptr, nullptr, nullptr, nullptr, nullptr, 2048, 2048);
}